// Round 1
// baseline (82577.612 us; speedup 1.0000x reference)
//
#include <hip/hip_runtime.h>
#include <stdint.h>

#define T_STEPS 16384
#define NDIM 256
#define MDIM 512
#define KP1 512
#define LOUT 256
#define G 16
#define TPB 256

typedef unsigned long long u64;
typedef unsigned int u32;

// ---- ws layout (float offsets) ----
constexpr size_t OFF_GH    = 0;                         // [512][1536] cached W_hh@M[q]+b_hh
constexpr size_t OFF_GHS   = 512ull * 1536;             // [1536] scratch gh (q==0 / startup)
constexpr size_t OFF_M     = OFF_GHS + 1536;            // [512][512] memory rows
constexpr size_t OFF_RING  = OFF_M + 512ull * 512;      // [4][1536] gi ring
constexpr size_t OFF_H     = OFF_RING + 4ull * 1536;    // [16384][512] hidden outputs
constexpr size_t OFF_VWT   = OFF_H + 16384ull * 512;    // [512][256] V_w transposed
constexpr size_t OFF_FLAGS = OFF_VWT + 512ull * 256;    // u64 flags after this

__device__ __forceinline__ float ld_cohf(const float* p) {
  return __hip_atomic_load(p, __ATOMIC_RELAXED, __HIP_MEMORY_SCOPE_AGENT);
}
__device__ __forceinline__ void st_cohf(float* p, float v) {
  __hip_atomic_store(p, v, __ATOMIC_RELAXED, __HIP_MEMORY_SCOPE_AGENT);
}
__device__ __forceinline__ u64 ld_flag(const u64* p) {
  return __hip_atomic_load(p, __ATOMIC_RELAXED, __HIP_MEMORY_SCOPE_AGENT);
}
__device__ __forceinline__ void st_flag(u64* p, u64 v) {
  __hip_atomic_store(p, v, __ATOMIC_RELEASE, __HIP_MEMORY_SCOPE_AGENT);
}

__device__ __forceinline__ float sigm(float x) {
  return __builtin_amdgcn_rcpf(1.0f + __expf(-x));
}
__device__ __forceinline__ float tanh_(float x) {
  return 1.0f - 2.0f * __builtin_amdgcn_rcpf(__expf(2.0f * x) + 1.0f);
}

__global__ __launch_bounds__(TPB, 2) void dmm_main(
    const float* __restrict__ X, const float* __restrict__ h0,
    const float* __restrict__ W_ih, const float* __restrict__ W_hh,
    const float* __restrict__ b_ih, const float* __restrict__ b_hh,
    const float* __restrict__ C_w, const float* __restrict__ C_b,
    float* __restrict__ ws)
{
  const int b   = blockIdx.x;
  const int tid = threadIdx.x;
  const int w   = tid >> 6;
  const int l   = tid & 63;

  float* GH   = ws + OFF_GH;
  float* GHS  = ws + OFF_GHS;
  float* Mrow = ws + OFF_M;
  float* RING = ws + OFF_RING;
  float* H    = ws + OFF_H;
  u64*   flags = (u64*)(ws + OFF_FLAGS);
  u64* flagS = flags;        // [16]
  u64* flagB = flags + 16;   // [2][16]
  u64* flagC = flags + 48;   // [2][16]

  __shared__ __align__(16) float hnew[MDIM];
  __shared__ __align__(16) float red[96 * 36];
  __shared__ u32 written[KP1];   // touched only by tid 0
  __shared__ u32 bc[4];

  // ---- persistent register-resident weight slices ----
  // gi: rows rl = w*24 + (l>>4)*6 + i (96/block), cols 16*(l&15)+k
  float wih[6][16];
  {
    int rbase = 96 * b + w * 24 + (l >> 4) * 6;
    int cbase = 16 * (l & 15);
#pragma unroll
    for (int i = 0; i < 6; i++)
#pragma unroll
      for (int k = 0; k < 16; k++)
        wih[i][k] = W_ih[(rbase + i) * NDIM + cbase + k];
  }
  // logits: rows rl = w*8 + (l>>5)*4 + i (32/block), cols 16*(l&31)+k
  float cw[4][16];
  {
    int rbase = 32 * b + w * 8 + (l >> 5) * 4;
    int cbase = 16 * (l & 31);
#pragma unroll
    for (int i = 0; i < 4; i++)
#pragma unroll
      for (int k = 0; k < 16; k++)
        cw[i][k] = C_w[(rbase + i) * MDIM + cbase + k];
  }

  for (int i = tid; i < KP1; i += TPB) written[i] = 0u;
  hnew[tid]       = h0[tid];
  hnew[tid + 256] = h0[tid + 256];
  __syncthreads();

  // ---- produce gi(s) = W_ih@x_s + b_ih (this block's 96 rows) into RING ----
  auto produce_gi = [&](int s) {
    int cbase = 16 * (l & 15);
    float xr[16];
#pragma unroll
    for (int k = 0; k < 16; k++) xr[k] = X[(size_t)s * NDIM + cbase + k];
    float p[6];
#pragma unroll
    for (int i = 0; i < 6; i++) {
      float a = 0.f;
#pragma unroll
      for (int k = 0; k < 16; k++) a = fmaf(wih[i][k], xr[k], a);
      p[i] = a;
    }
    int rl = w * 24 + (l >> 4) * 6;
    int lc = l & 15;
#pragma unroll
    for (int i = 0; i < 6; i++) red[(rl + i) * 20 + lc] = p[i];
    __syncthreads();
    if (tid < 96) {
      float a = 0.f;
#pragma unroll
      for (int k = 0; k < 16; k += 4) {
        float4 v = *(const float4*)&red[tid * 20 + k];
        a += v.x + v.y + v.z + v.w;
      }
      a += b_ih[96 * b + tid];
      st_cohf(&RING[(size_t)(s & 3) * 1536 + 96 * b + tid], a);
    }
    __syncthreads();
  };

  // ---- compute gh = W_hh@hnew + b_hh (this block's 96 rows) into dst ----
  auto compute_gh = [&](float* dst) {
    int cb = 16 * (l & 31);
    float hr[16];
#pragma unroll
    for (int k = 0; k < 16; k += 4) *(float4*)&hr[k] = *(const float4*)&hnew[cb + k];
    int rb = 96 * b + w * 24 + (l >> 5) * 12;
    float p[12];
#pragma unroll
    for (int i = 0; i < 12; i++) {
      float a = 0.f;
      const float* wr = &W_hh[(size_t)(rb + i) * MDIM + cb];
#pragma unroll
      for (int k = 0; k < 16; k++) a = fmaf(wr[k], hr[k], a);
      p[i] = a;
    }
    int rl = w * 24 + (l >> 5) * 12;
    int lc = l & 31;
#pragma unroll
    for (int i = 0; i < 12; i++) red[(rl + i) * 36 + lc] = p[i];
    __syncthreads();
    if (tid < 96) {
      float a = 0.f;
#pragma unroll
      for (int k = 0; k < 32; k += 4) {
        float4 v = *(const float4*)&red[tid * 36 + k];
        a += v.x + v.y + v.z + v.w;
      }
      a += b_hh[96 * b + tid];
      st_cohf(&dst[96 * b + tid], a);
    }
    __syncthreads();
  };

  // ---- startup: gi(0), gi(1), gh(h0) ----
  produce_gi(0);
  produce_gi(1);
  compute_gh(GHS);
  if (tid == 0) st_flag(&flagS[b], 1ull);
  if (w == 0) {
    int guard = 0;
    bool done = false;
    while (!done) {
      u64 v = (l < G) ? ld_flag(&flagS[l]) : 1ull;
      done = (__ballot((int)(v == 1ull)) == ~0ull);
      if (++guard > (1 << 25)) break;
    }
  }
  __syncthreads();
  __threadfence();

  const float* ghsrc = GHS;
  bool prevReadHit = false;
  int  qprev = 0;

  for (int t = 0; t < T_STEPS; ++t) {
    // dependent loads: gh row (plain — GH rows are write-once, first-touch-after-write)
    float g0 = (ghsrc == GHS) ? ld_cohf(&ghsrc[tid])        : ghsrc[tid];
    float g1 = (ghsrc == GHS) ? ld_cohf(&ghsrc[tid + 256])  : ghsrc[tid + 256];
    float g2 = (ghsrc == GHS) ? ld_cohf(&ghsrc[512 + tid])  : ghsrc[512 + tid];
    float g3 = (ghsrc == GHS) ? ld_cohf(&ghsrc[512 + tid + 256])  : ghsrc[512 + tid + 256];
    float g4 = (ghsrc == GHS) ? ld_cohf(&ghsrc[1024 + tid]) : ghsrc[1024 + tid];
    float g5 = (ghsrc == GHS) ? ld_cohf(&ghsrc[1024 + tid + 256]) : ghsrc[1024 + tid + 256];
    float m0 = 0.f, m1 = 0.f;
    if (prevReadHit) {
      m0 = Mrow[(size_t)qprev * 512 + tid];          // write-once rows: plain OK
      m1 = Mrow[(size_t)qprev * 512 + tid + 256];
    }
    // gi loads (ring is rewritten -> coherent loads)
    const float* gi = &RING[(size_t)(t & 3) * 1536];
    float i0 = ld_cohf(&gi[tid]);
    float i1 = ld_cohf(&gi[tid + 256]);
    float i2 = ld_cohf(&gi[512 + tid]);
    float i3 = ld_cohf(&gi[512 + tid + 256]);
    float i4 = ld_cohf(&gi[1024 + tid]);
    float i5 = ld_cohf(&gi[1024 + tid + 256]);

    // overlap load latency with next-next gi production
    if (t + 2 < T_STEPS) produce_gi(t + 2);

    // lagged H write for read-hit step t-1
    if (prevReadHit) {
      __builtin_nontemporal_store(m0, &H[(size_t)(t - 1) * 512 + tid]);
      __builtin_nontemporal_store(m1, &H[(size_t)(t - 1) * 512 + tid + 256]);
    }

    // gates (torch GRU semantics)
    float hp0 = prevReadHit ? m0 : hnew[tid];
    float hp1 = prevReadHit ? m1 : hnew[tid + 256];
    float r0 = sigm(i0 + g0), r1 = sigm(i1 + g1);
    float z0 = sigm(i2 + g2), z1 = sigm(i3 + g3);
    float n0 = tanh_(fmaf(r0, g4, i4)), n1 = tanh_(fmaf(r1, g5, i5));
    float hn0 = fmaf(z0, hp0 - n0, n0);
    float hn1 = fmaf(z1, hp1 - n1, n1);
    hnew[tid]       = hn0;
    hnew[tid + 256] = hn1;
    __syncthreads();

    // logits slice (32 rows) from register-resident C_w
    {
      int cb = 16 * (l & 31);
      float hr[16];
#pragma unroll
      for (int k = 0; k < 16; k += 4) *(float4*)&hr[k] = *(const float4*)&hnew[cb + k];
      float p0 = 0.f, p1 = 0.f, p2 = 0.f, p3 = 0.f;
#pragma unroll
      for (int k = 0; k < 16; k++) {
        p0 = fmaf(cw[0][k], hr[k], p0);
        p1 = fmaf(cw[1][k], hr[k], p1);
        p2 = fmaf(cw[2][k], hr[k], p2);
        p3 = fmaf(cw[3][k], hr[k], p3);
      }
      int rl = w * 8 + (l >> 5) * 4;
      int lc = l & 31;
      red[(rl + 0) * 36 + lc] = p0;
      red[(rl + 1) * 36 + lc] = p1;
      red[(rl + 2) * 36 + lc] = p2;
      red[(rl + 3) * 36 + lc] = p3;
    }
    __syncthreads();
    if (tid < 32) {
      double a = 0.0;   // double final reduce: argmax robustness
#pragma unroll
      for (int k = 0; k < 32; k += 4) {
        float4 v = *(const float4*)&red[tid * 36 + k];
        a += (double)v.x + (double)v.y + (double)v.z + (double)v.w;
      }
      a += (double)C_b[32 * b + tid];
      float af = (float)a;
      u32 bits = __float_as_uint(af);
      u32 ord  = (bits & 0x80000000u) ? ~bits : (bits | 0x80000000u);
      int gidx = 32 * b + tid;
      u64 key = ((u64)ord << 9) | (u64)(511 - gidx);
#pragma unroll
      for (int off = 16; off >= 1; off >>= 1) {
        u64 other = __shfl_xor(key, off, 64);
        if (other > key) key = other;
      }
      if (tid == 0) st_flag(&flagB[(size_t)(t & 1) * 16 + b], ((u64)(t + 1) << 41) | key);
    }

    // poll all blocks' keys, pick global argmax (deterministic, replicated)
    if (w == 0) {
      u64 v = 0;
      int guard = 0;
      for (;;) {
        v = (l < G) ? ld_flag(&flagB[(size_t)(t & 1) * 16 + l]) : 0;
        bool ok = (l >= G) || ((v >> 41) == (u64)(t + 1));
        if (__ballot((int)ok) == ~0ull) break;
        if (++guard > (1 << 25)) break;
      }
      u64 key = (l < G) ? (v & ((1ull << 41) - 1)) : 0;
#pragma unroll
      for (int off = 8; off >= 1; off >>= 1) {
        u64 other = __shfl_xor(key, off, 64);
        if (other > key) key = other;
      }
      if (l == 0) {
        int q = 511 - (int)(key & 0x1FFu);
        u32 wr = written[q];
        u32 fresh = (q > 0 && wr == 0u) ? 1u : 0u;
        u32 rhit  = (q > 0 && wr != 0u) ? 1u : 0u;
        if (fresh) written[q] = 1u;
        bc[0] = (u32)q | (fresh << 16) | (rhit << 17);
      }
    }
    __syncthreads();
    __threadfence();
    u32 info = bc[0];
    int  q     = (int)(info & 0xFFFFu);
    bool fresh = (info >> 16) & 1u;
    bool rhit  = (info >> 17) & 1u;

    if (!rhit) {
      // h_out = h_new: emit H[t] now; compute gh for next step (rare path)
      __builtin_nontemporal_store(hnew[tid],       &H[(size_t)t * 512 + tid]);
      __builtin_nontemporal_store(hnew[tid + 256], &H[(size_t)t * 512 + tid + 256]);
      float* dst;
      if (fresh) {
        if (tid < 32) st_cohf(&Mrow[(size_t)q * 512 + 32 * b + tid], hnew[32 * b + tid]);
        dst = &GH[(size_t)q * 1536];
      } else {
        dst = GHS;
      }
      compute_gh(dst);
      if (tid == 0) st_flag(&flagC[(size_t)(t & 1) * 16 + b], (u64)(t + 1));
      if (w == 0) {
        int guard = 0;
        for (;;) {
          u64 v = (l < G) ? ld_flag(&flagC[(size_t)(t & 1) * 16 + l]) : 0;
          bool ok = (l >= G) || (v == (u64)(t + 1));
          if (__ballot((int)ok) == ~0ull) break;
          if (++guard > (1 << 25)) break;
        }
      }
      __syncthreads();
      __threadfence();
      ghsrc = dst;
      prevReadHit = false;
    } else {
      ghsrc = &GH[(size_t)q * 1536];
      prevReadHit = true;
      qprev = q;
    }
  }

  // epilogue: H[T-1] for trailing read-hit
  if (prevReadHit) {
    float a = Mrow[(size_t)qprev * 512 + tid];
    float c = Mrow[(size_t)qprev * 512 + tid + 256];
    __builtin_nontemporal_store(a, &H[(size_t)(T_STEPS - 1) * 512 + tid]);
    __builtin_nontemporal_store(c, &H[(size_t)(T_STEPS - 1) * 512 + tid + 256]);
  }
}

// ---- V_w transpose: VwT[k][l] = V_w[l][k] ----
__global__ void vw_transpose(const float* __restrict__ Vw, float* __restrict__ VwT) {
  int idx = blockIdx.x * 256 + threadIdx.x;     // over 512*256
  int kk = idx >> 8, ll = idx & 255;
  VwT[idx] = Vw[(size_t)ll * MDIM + kk];
}

// ---- Y = H @ V_w^T + V_b ----
__global__ __launch_bounds__(256) void y_gemm(const float* __restrict__ Hm,
                                              const float* __restrict__ VwT,
                                              const float* __restrict__ Vb,
                                              float* __restrict__ Y) {
  int t0 = blockIdx.x * 16;
  int tid = threadIdx.x;
  __shared__ __align__(16) float hs[16 * MDIM];
  for (int i = tid; i < 16 * MDIM; i += 256)
    hs[i] = Hm[(size_t)t0 * MDIM + i];
  __syncthreads();
  float acc[16];
  float vb = Vb[tid];
#pragma unroll
  for (int r = 0; r < 16; r++) acc[r] = vb;
  for (int k = 0; k < MDIM; k += 4) {
    float v0 = VwT[(size_t)(k + 0) * LOUT + tid];
    float v1 = VwT[(size_t)(k + 1) * LOUT + tid];
    float v2 = VwT[(size_t)(k + 2) * LOUT + tid];
    float v3 = VwT[(size_t)(k + 3) * LOUT + tid];
#pragma unroll
    for (int r = 0; r < 16; r++) {
      float4 h4 = *(const float4*)&hs[r * MDIM + k];
      acc[r] = fmaf(h4.x, v0, fmaf(h4.y, v1, fmaf(h4.z, v2, fmaf(h4.w, v3, acc[r]))));
    }
  }
#pragma unroll
  for (int r = 0; r < 16; r++)
    Y[(size_t)(t0 + r) * LOUT + tid] = acc[r];
}

extern "C" void kernel_launch(void* const* d_in, const int* in_sizes, int n_in,
                              void* d_out, int out_size, void* d_ws, size_t ws_size,
                              hipStream_t stream) {
  const float* X    = (const float*)d_in[0];
  const float* h0   = (const float*)d_in[1];
  const float* W_ih = (const float*)d_in[2];
  const float* W_hh = (const float*)d_in[3];
  const float* b_ih = (const float*)d_in[4];
  const float* b_hh = (const float*)d_in[5];
  const float* C_w  = (const float*)d_in[6];
  const float* C_b  = (const float*)d_in[7];
  const float* V_w  = (const float*)d_in[8];
  const float* V_b  = (const float*)d_in[9];
  float* ws  = (float*)d_ws;
  float* VwT = ws + OFF_VWT;
  float* Hm  = ws + OFF_H;

  hipLaunchKernelGGL(vw_transpose, dim3(512), dim3(256), 0, stream, V_w, VwT);
  hipLaunchKernelGGL(dmm_main, dim3(G), dim3(TPB), 0, stream,
                     X, h0, W_ih, W_hh, b_ih, b_hh, C_w, C_b, ws);
  hipLaunchKernelGGL(y_gemm, dim3(T_STEPS / 16), dim3(256), 0, stream,
                     Hm, VwT, V_b, (float*)d_out);
}

// Round 2
// 55146.967 us; speedup vs baseline: 1.4974x; 1.4974x over previous
//
#include <hip/hip_runtime.h>
#include <stdint.h>

#define T_STEPS 16384
#define NDIM 256
#define MDIM 512
#define KP1 512
#define LOUT 256
#define G 16
#define TPB 256

typedef unsigned long long u64;
typedef unsigned int u32;

// ---- ws layout (float offsets) ----
constexpr size_t OFF_GH    = 0;                         // [512][1536] cached W_hh@M[q]+b_hh
constexpr size_t OFF_GHS   = 512ull * 1536;             // [1536] scratch gh (q==0 / startup)
constexpr size_t OFF_M     = OFF_GHS + 1536;            // [512][512] memory rows
constexpr size_t OFF_RING  = OFF_M + 512ull * 512;      // [4][1536] gi ring
constexpr size_t OFF_H     = OFF_RING + 4ull * 1536;    // [16384][512] hidden outputs
constexpr size_t OFF_VWT   = OFF_H + 16384ull * 512;    // [512][256] V_w transposed
constexpr size_t OFF_FLAGS = OFF_VWT + 512ull * 256;    // u64 flags after this

__device__ __forceinline__ float ld_cohf(const float* p) {
  return __hip_atomic_load(p, __ATOMIC_RELAXED, __HIP_MEMORY_SCOPE_AGENT);
}
__device__ __forceinline__ void st_cohf(float* p, float v) {
  __hip_atomic_store(p, v, __ATOMIC_RELAXED, __HIP_MEMORY_SCOPE_AGENT);
}
__device__ __forceinline__ u64 ld_flag(const u64* p) {
  return __hip_atomic_load(p, __ATOMIC_RELAXED, __HIP_MEMORY_SCOPE_AGENT);
}
__device__ __forceinline__ void st_flag_rel(u64* p, u64 v) {
  __hip_atomic_store(p, v, __ATOMIC_RELEASE, __HIP_MEMORY_SCOPE_AGENT);
}
__device__ __forceinline__ void st_flag_rlx(u64* p, u64 v) {
  __hip_atomic_store(p, v, __ATOMIC_RELAXED, __HIP_MEMORY_SCOPE_AGENT);
}

__device__ __forceinline__ float sigm(float x) {
  return __builtin_amdgcn_rcpf(1.0f + __expf(-x));
}
__device__ __forceinline__ float tanh_(float x) {
  return 1.0f - 2.0f * __builtin_amdgcn_rcpf(__expf(2.0f * x) + 1.0f);
}

__global__ __launch_bounds__(TPB, 2) void dmm_main(
    const float* __restrict__ X, const float* __restrict__ h0,
    const float* __restrict__ W_ih, const float* __restrict__ W_hh,
    const float* __restrict__ b_ih, const float* __restrict__ b_hh,
    const float* __restrict__ C_w, const float* __restrict__ C_b,
    float* __restrict__ ws)
{
  const int b   = blockIdx.x;
  const int tid = threadIdx.x;
  const int w   = tid >> 6;
  const int l   = tid & 63;

  float* GH   = ws + OFF_GH;
  float* GHS  = ws + OFF_GHS;
  float* Mrow = ws + OFF_M;
  float* RING = ws + OFF_RING;
  float* H    = ws + OFF_H;
  u64*   flags = (u64*)(ws + OFF_FLAGS);
  u64* flagS = flags;        // [16]
  u64* flagB = flags + 16;   // [2][16]
  u64* flagC = flags + 48;   // [2][16]

  __shared__ __align__(16) float hnew[MDIM];
  __shared__ __align__(16) float red[96 * 36];
  __shared__ u32 written[KP1];   // touched only by lane handling argmax (replicated per block)
  __shared__ u32 bc[4];

  // ---- persistent register-resident weight slices ----
  // gi: rows rl = w*24 + (l>>4)*6 + i (96/block), cols 16*(l&15)+k
  float wih[6][16];
  {
    int rbase = 96 * b + w * 24 + (l >> 4) * 6;
    int cbase = 16 * (l & 15);
#pragma unroll
    for (int i = 0; i < 6; i++)
#pragma unroll
      for (int k = 0; k < 16; k++)
        wih[i][k] = W_ih[(rbase + i) * NDIM + cbase + k];
  }
  // logits: rows rl = w*8 + (l>>5)*4 + i (32/block), cols 16*(l&31)+k
  float cw[4][16];
  {
    int rbase = 32 * b + w * 8 + (l >> 5) * 4;
    int cbase = 16 * (l & 31);
#pragma unroll
    for (int i = 0; i < 4; i++)
#pragma unroll
      for (int k = 0; k < 16; k++)
        cw[i][k] = C_w[(rbase + i) * MDIM + cbase + k];
  }

  for (int i = tid; i < KP1; i += TPB) written[i] = 0u;
  hnew[tid]       = h0[tid];
  hnew[tid + 256] = h0[tid + 256];
  __syncthreads();

  // ---- produce gi(s) = W_ih@x_s + b_ih (this block's 96 rows) into RING ----
  auto produce_gi = [&](int s) {
    int cbase = 16 * (l & 15);
    float xr[16];
#pragma unroll
    for (int k = 0; k < 16; k++) xr[k] = X[(size_t)s * NDIM + cbase + k];
    float p[6];
#pragma unroll
    for (int i = 0; i < 6; i++) {
      float a = 0.f;
#pragma unroll
      for (int k = 0; k < 16; k++) a = fmaf(wih[i][k], xr[k], a);
      p[i] = a;
    }
    int rl = w * 24 + (l >> 4) * 6;
    int lc = l & 15;
#pragma unroll
    for (int i = 0; i < 6; i++) red[(rl + i) * 20 + lc] = p[i];
    __syncthreads();
    if (tid < 96) {
      float a = 0.f;
#pragma unroll
      for (int k = 0; k < 16; k += 4) {
        float4 v = *(const float4*)&red[tid * 20 + k];
        a += v.x + v.y + v.z + v.w;
      }
      a += b_ih[96 * b + tid];
      st_cohf(&RING[(size_t)(s & 3) * 1536 + 96 * b + tid], a);
    }
    __syncthreads();
  };

  // ---- compute gh = W_hh@hnew + b_hh (this block's 96 rows) into dst ----
  auto compute_gh = [&](float* dst) {
    int cb = 16 * (l & 31);
    float hr[16];
#pragma unroll
    for (int k = 0; k < 16; k += 4) *(float4*)&hr[k] = *(const float4*)&hnew[cb + k];
    int rb = 96 * b + w * 24 + (l >> 5) * 12;
    float p[12];
#pragma unroll
    for (int i = 0; i < 12; i++) {
      float a = 0.f;
      const float* wr = &W_hh[(size_t)(rb + i) * MDIM + cb];
#pragma unroll
      for (int k = 0; k < 16; k++) a = fmaf(wr[k], hr[k], a);
      p[i] = a;
    }
    int rl = w * 24 + (l >> 5) * 12;
    int lc = l & 31;
#pragma unroll
    for (int i = 0; i < 12; i++) red[(rl + i) * 36 + lc] = p[i];
    __syncthreads();
    if (tid < 96) {
      float a = 0.f;
#pragma unroll
      for (int k = 0; k < 32; k += 4) {
        float4 v = *(const float4*)&red[tid * 36 + k];
        a += v.x + v.y + v.z + v.w;
      }
      a += b_hh[96 * b + tid];
      st_cohf(&dst[96 * b + tid], a);
    }
    __syncthreads();
  };

  // ---- startup: gi(0), gi(1), gh(h0) ----
  produce_gi(0);
  produce_gi(1);
  compute_gh(GHS);
  if (tid == 0) st_flag_rel(&flagS[b], 1ull);
  if (w == 0) {
    int guard = 0;
    bool done = false;
    while (!done) {
      u64 v = (l < G) ? ld_flag(&flagS[l]) : 1ull;
      done = (__ballot((int)(v == 1ull)) == ~0ull);
      if (++guard > (1 << 22)) break;
    }
  }
  __syncthreads();

  const float* ghsrc = GHS;
  bool prevReadHit = false;
  int  qprev = 0;

  for (int t = 0; t < T_STEPS; ++t) {
    // dependent sc1 loads (coherent at MALL; issue all up front)
    float g0 = ld_cohf(&ghsrc[tid]);
    float g1 = ld_cohf(&ghsrc[tid + 256]);
    float g2 = ld_cohf(&ghsrc[512 + tid]);
    float g3 = ld_cohf(&ghsrc[512 + tid + 256]);
    float g4 = ld_cohf(&ghsrc[1024 + tid]);
    float g5 = ld_cohf(&ghsrc[1024 + tid + 256]);
    float m0 = 0.f, m1 = 0.f;
    if (prevReadHit) {
      m0 = ld_cohf(&Mrow[(size_t)qprev * 512 + tid]);
      m1 = ld_cohf(&Mrow[(size_t)qprev * 512 + tid + 256]);
    }
    const float* gi = &RING[(size_t)(t & 3) * 1536];
    float i0 = ld_cohf(&gi[tid]);
    float i1 = ld_cohf(&gi[tid + 256]);
    float i2 = ld_cohf(&gi[512 + tid]);
    float i3 = ld_cohf(&gi[512 + tid + 256]);
    float i4 = ld_cohf(&gi[1024 + tid]);
    float i5 = ld_cohf(&gi[1024 + tid + 256]);

    // lagged H write for read-hit step t-1 (uses m0/m1)
    if (prevReadHit) {
      __builtin_nontemporal_store(m0, &H[(size_t)(t - 1) * 512 + tid]);
      __builtin_nontemporal_store(m1, &H[(size_t)(t - 1) * 512 + tid + 256]);
    }

    // gates (torch GRU semantics)
    float hp0 = prevReadHit ? m0 : hnew[tid];
    float hp1 = prevReadHit ? m1 : hnew[tid + 256];
    float r0 = sigm(i0 + g0), r1 = sigm(i1 + g1);
    float z0 = sigm(i2 + g2), z1 = sigm(i3 + g3);
    float n0 = tanh_(fmaf(r0, g4, i4)), n1 = tanh_(fmaf(r1, g5, i5));
    float hn0 = fmaf(z0, hp0 - n0, n0);
    float hn1 = fmaf(z1, hp1 - n1, n1);
    hnew[tid]       = hn0;
    hnew[tid + 256] = hn1;
    __syncthreads();

    // logits slice (32 rows) from register-resident C_w
    {
      int cb = 16 * (l & 31);
      float hr[16];
#pragma unroll
      for (int k = 0; k < 16; k += 4) *(float4*)&hr[k] = *(const float4*)&hnew[cb + k];
      float p0 = 0.f, p1 = 0.f, p2 = 0.f, p3 = 0.f;
#pragma unroll
      for (int k = 0; k < 16; k++) {
        p0 = fmaf(cw[0][k], hr[k], p0);
        p1 = fmaf(cw[1][k], hr[k], p1);
        p2 = fmaf(cw[2][k], hr[k], p2);
        p3 = fmaf(cw[3][k], hr[k], p3);
      }
      int rl = w * 8 + (l >> 5) * 4;
      int lc = l & 31;
      red[(rl + 0) * 36 + lc] = p0;
      red[(rl + 1) * 36 + lc] = p1;
      red[(rl + 2) * 36 + lc] = p2;
      red[(rl + 3) * 36 + lc] = p3;
    }
    __syncthreads();
    if (tid < 32) {
      double a = 0.0;   // double final reduce: argmax robustness
#pragma unroll
      for (int k = 0; k < 32; k += 4) {
        float4 v = *(const float4*)&red[tid * 36 + k];
        a += (double)v.x + (double)v.y + (double)v.z + (double)v.w;
      }
      a += (double)C_b[32 * b + tid];
      float af = (float)a;
      u32 bits = __float_as_uint(af);
      u32 ord  = (bits & 0x80000000u) ? ~bits : (bits | 0x80000000u);
      int gidx = 32 * b + tid;
      u64 key = ((u64)ord << 9) | (u64)(511 - gidx);
#pragma unroll
      for (int off = 16; off >= 1; off >>= 1) {
        u64 other = __shfl_xor(key, off, 64);
        if (other > key) key = other;
      }
      // key is self-contained (epoch+key in one word): RELAXED store, no drain
      if (tid == 0) st_flag_rlx(&flagB[(size_t)(t & 1) * 16 + b], ((u64)(t + 1) << 41) | key);
    }
    __syncthreads();   // red reuse guard (produce_gi writes red next)

    // overlap next-next gi production with cross-XCD flag propagation
    if (t + 2 < T_STEPS) produce_gi(t + 2);

    // poll all blocks' keys, pick global argmax (deterministic, replicated)
    if (w == 0) {
      u64 v = 0;
      int guard = 0;
      for (;;) {
        v = (l < G) ? ld_flag(&flagB[(size_t)(t & 1) * 16 + l]) : 0;
        bool ok = (l >= G) || ((v >> 41) == (u64)(t + 1));
        if (__ballot((int)ok) == ~0ull) break;
        if (++guard > (1 << 22)) break;
      }
      u64 key = (l < G) ? (v & ((1ull << 41) - 1)) : 0;
#pragma unroll
      for (int off = 8; off >= 1; off >>= 1) {
        u64 other = __shfl_xor(key, off, 64);
        if (other > key) key = other;
      }
      if (l == 0) {
        int q = 511 - (int)(key & 0x1FFu);
        u32 wr = written[q];
        u32 fresh = (q > 0 && wr == 0u) ? 1u : 0u;
        u32 rhit  = (q > 0 && wr != 0u) ? 1u : 0u;
        if (fresh) written[q] = 1u;
        bc[0] = (u32)q | (fresh << 16) | (rhit << 17);
      }
    }
    __syncthreads();
    u32 info = bc[0];
    int  q     = (int)(info & 0xFFFFu);
    bool fresh = (info >> 16) & 1u;
    bool rhit  = (info >> 17) & 1u;

    if (!rhit) {
      // h_out = h_new: emit H[t] now; compute gh for next step (rare path)
      __builtin_nontemporal_store(hnew[tid],       &H[(size_t)t * 512 + tid]);
      __builtin_nontemporal_store(hnew[tid + 256], &H[(size_t)t * 512 + tid + 256]);
      float* dst;
      if (fresh) {
        if (tid < 32) st_cohf(&Mrow[(size_t)q * 512 + 32 * b + tid], hnew[32 * b + tid]);
        dst = &GH[(size_t)q * 1536];
      } else {
        dst = GHS;
      }
      compute_gh(dst);
      // payload (GH/GHS/Mrow sc1 stores) must precede flag: RELEASE here
      if (tid == 0) st_flag_rel(&flagC[(size_t)(t & 1) * 16 + b], (u64)(t + 1));
      if (w == 0) {
        int guard = 0;
        for (;;) {
          u64 v = (l < G) ? ld_flag(&flagC[(size_t)(t & 1) * 16 + l]) : 0;
          bool ok = (l >= G) || (v == (u64)(t + 1));
          if (__ballot((int)ok) == ~0ull) break;
          if (++guard > (1 << 22)) break;
        }
      }
      __syncthreads();
      ghsrc = dst;
      prevReadHit = false;
    } else {
      ghsrc = &GH[(size_t)q * 1536];
      prevReadHit = true;
      qprev = q;
    }
  }

  // epilogue: H[T-1] for trailing read-hit
  if (prevReadHit) {
    float a = ld_cohf(&Mrow[(size_t)qprev * 512 + tid]);
    float c = ld_cohf(&Mrow[(size_t)qprev * 512 + tid + 256]);
    __builtin_nontemporal_store(a, &H[(size_t)(T_STEPS - 1) * 512 + tid]);
    __builtin_nontemporal_store(c, &H[(size_t)(T_STEPS - 1) * 512 + tid + 256]);
  }
}

// ---- V_w transpose: VwT[k][l] = V_w[l][k] ----
__global__ void vw_transpose(const float* __restrict__ Vw, float* __restrict__ VwT) {
  int idx = blockIdx.x * 256 + threadIdx.x;     // over 512*256
  int kk = idx >> 8, ll = idx & 255;
  VwT[idx] = Vw[(size_t)ll * MDIM + kk];
}

// ---- Y = H @ V_w^T + V_b ----
__global__ __launch_bounds__(256) void y_gemm(const float* __restrict__ Hm,
                                              const float* __restrict__ VwT,
                                              const float* __restrict__ Vb,
                                              float* __restrict__ Y) {
  int t0 = blockIdx.x * 16;
  int tid = threadIdx.x;
  __shared__ __align__(16) float hs[16 * MDIM];
  for (int i = tid; i < 16 * MDIM; i += 256)
    hs[i] = Hm[(size_t)t0 * MDIM + i];
  __syncthreads();
  float acc[16];
  float vb = Vb[tid];
#pragma unroll
  for (int r = 0; r < 16; r++) acc[r] = vb;
  for (int k = 0; k < MDIM; k += 4) {
    float v0 = VwT[(size_t)(k + 0) * LOUT + tid];
    float v1 = VwT[(size_t)(k + 1) * LOUT + tid];
    float v2 = VwT[(size_t)(k + 2) * LOUT + tid];
    float v3 = VwT[(size_t)(k + 3) * LOUT + tid];
#pragma unroll
    for (int r = 0; r < 16; r++) {
      float4 h4 = *(const float4*)&hs[r * MDIM + k];
      acc[r] = fmaf(h4.x, v0, fmaf(h4.y, v1, fmaf(h4.z, v2, fmaf(h4.w, v3, acc[r]))));
    }
  }
#pragma unroll
  for (int r = 0; r < 16; r++)
    Y[(size_t)(t0 + r) * LOUT + tid] = acc[r];
}

extern "C" void kernel_launch(void* const* d_in, const int* in_sizes, int n_in,
                              void* d_out, int out_size, void* d_ws, size_t ws_size,
                              hipStream_t stream) {
  const float* X    = (const float*)d_in[0];
  const float* h0   = (const float*)d_in[1];
  const float* W_ih = (const float*)d_in[2];
  const float* W_hh = (const float*)d_in[3];
  const float* b_ih = (const float*)d_in[4];
  const float* b_hh = (const float*)d_in[5];
  const float* C_w  = (const float*)d_in[6];
  const float* C_b  = (const float*)d_in[7];
  const float* V_w  = (const float*)d_in[8];
  const float* V_b  = (const float*)d_in[9];
  float* ws  = (float*)d_ws;
  float* VwT = ws + OFF_VWT;
  float* Hm  = ws + OFF_H;

  hipLaunchKernelGGL(vw_transpose, dim3(512), dim3(256), 0, stream, V_w, VwT);
  hipLaunchKernelGGL(dmm_main, dim3(G), dim3(TPB), 0, stream,
                     X, h0, W_ih, W_hh, b_ih, b_hh, C_w, C_b, ws);
  hipLaunchKernelGGL(y_gemm, dim3(T_STEPS / 16), dim3(256), 0, stream,
                     Hm, VwT, V_b, (float*)d_out);
}